// Round 1
// baseline (383.737 us; speedup 1.0000x reference)
//
#include <hip/hip_runtime.h>
#include <hip/hip_bf16.h>

// Problem constants
#define Bn    2
#define Tdim  2048
#define Cdim  1024
#define Hn    16
#define HSd   64
#define Mrows 4096   // B*T

typedef unsigned short u16;
typedef __attribute__((ext_vector_type(8))) short short8;
typedef __attribute__((ext_vector_type(4))) float f32x4;

__device__ __forceinline__ u16 f2bf(float f) {
  union { __hip_bfloat16 h; u16 u; } cv;
  cv.h = __float2bfloat16(f);
  return cv.u;
}

#define GLOAD_LDS16(g, l)                                                     \
  __builtin_amdgcn_global_load_lds(                                           \
      (const __attribute__((address_space(1))) void*)(g),                     \
      (__attribute__((address_space(3))) void*)(l), 16, 0, 0)

// ---------------------------------------------------------------------------
// x (fp32, M x K row-major) -> bf16
__global__ __launch_bounds__(256) void k_convert_x(const float* __restrict__ x,
                                                   u16* __restrict__ xb) {
  int i = blockIdx.x * 256 + threadIdx.x;  // one float4 per thread
  float4 v = ((const float4*)x)[i];
  unsigned o0 = (unsigned)f2bf(v.x) | ((unsigned)f2bf(v.y) << 16);
  unsigned o1 = (unsigned)f2bf(v.z) | ((unsigned)f2bf(v.w) << 16);
  ((uint2*)xb)[i] = make_uint2(o0, o1);
}

// in: (R x Cc) fp32 row-major -> out: (Cc x R) bf16 row-major (i.e. N-major weights)
__global__ __launch_bounds__(256) void k_transpose_w(const float* __restrict__ in,
                                                     u16* __restrict__ out,
                                                     int R, int Cc) {
  __shared__ float tile[64][65];
  int c0 = blockIdx.x * 64, r0 = blockIdx.y * 64;
  int lc = threadIdx.x & 63, l0 = threadIdx.x >> 6;
  for (int rr = l0; rr < 64; rr += 4)
    tile[rr][lc] = in[(size_t)(r0 + rr) * Cc + c0 + lc];
  __syncthreads();
  for (int rr = l0; rr < 64; rr += 4)
    out[(size_t)(c0 + rr) * R + r0 + lc] = f2bf(tile[lc][rr]);
}

// Vh: [BH][T][64] bf16 -> Vt: [BH][64][T] bf16
__global__ __launch_bounds__(256) void k_transpose_v(const u16* __restrict__ Vh,
                                                     u16* __restrict__ Vt) {
  __shared__ u16 tile[64][72];
  int bh = blockIdx.y, t0 = blockIdx.x * 64;
  int lc = threadIdx.x & 63, l0 = threadIdx.x >> 6;
  const u16* src = Vh + (size_t)bh * Tdim * HSd;
  u16* dst = Vt + (size_t)bh * HSd * Tdim;
  for (int rr = l0; rr < 64; rr += 4)
    tile[rr][lc] = src[(size_t)(t0 + rr) * HSd + lc];
  __syncthreads();
  for (int dd = l0; dd < 64; dd += 4)
    dst[(size_t)dd * Tdim + t0 + lc] = tile[lc][dd];
}

// ---------------------------------------------------------------------------
// m97-structure GEMM: C[M,N] = A[M,K](bf16) * Bt[N,K](bf16)^T
// EPI 0: qkv epilogue (bias + RoPE, write Q/K head-major + V head-major, bf16)
// EPI 1: proj epilogue (bias, fp32 out)
template <int EPI>
__global__ __launch_bounds__(256, 2) void k_gemm(
    const u16* __restrict__ A, const u16* __restrict__ Bt,
    const float* __restrict__ bias, const float* __restrict__ cosT,
    const float* __restrict__ sinT, u16* __restrict__ Qh, u16* __restrict__ Kh,
    u16* __restrict__ Vh, float* __restrict__ Out, int Ndim, int Kdim) {
  __shared__ u16 As[128 * 32];
  __shared__ u16 Bs[128 * 32];
  const int tid = threadIdx.x;
  const int wid = tid >> 6, lane = tid & 63;
  const int m0 = blockIdx.x * 128, n0 = blockIdx.y * 128;
  const int wm = (wid >> 1) * 64, wn = (wid & 1) * 64;
  const int lr = lane & 15, lg = lane >> 4;

  f32x4 acc[4][4] = {};

  const u16* Ag = A + (size_t)m0 * Kdim;
  const u16* Bg = Bt + (size_t)n0 * Kdim;
  const int srow = lane >> 2, ske = (lane & 3) * 8;

  for (int k0 = 0; k0 < Kdim; k0 += 32) {
    // stage 128x32 A-tile + 128x32 B-tile (8 KB each), linear LDS,
    // wave-uniform LDS base + lane*16B (global_load_lds contract)
    for (int c = wid; c < 8; c += 4) {
      int row = c * 16 + srow;
      GLOAD_LDS16(Ag + (size_t)row * Kdim + k0 + ske, As + c * 512);
      GLOAD_LDS16(Bg + (size_t)row * Kdim + k0 + ske, Bs + c * 512);
    }
    __syncthreads();
    short8 a[4], b[4];
#pragma unroll
    for (int i = 0; i < 4; i++)
      a[i] = *(const short8*)(As + (wm + i * 16 + lr) * 32 + 8 * lg);
#pragma unroll
    for (int j = 0; j < 4; j++)
      b[j] = *(const short8*)(Bs + (wn + j * 16 + lr) * 32 + 8 * lg);
#pragma unroll
    for (int i = 0; i < 4; i++)
#pragma unroll
      for (int j = 0; j < 4; j++)
        acc[i][j] =
            __builtin_amdgcn_mfma_f32_16x16x32_bf16(a[i], b[j], acc[i][j], 0, 0, 0);
    __syncthreads();
  }

  const int nbase = n0 + wn;  // multiple of 64: one head-dim block per wave
  if (EPI == 0) {
    const int sec = nbase >> 10;         // 0=q 1=k 2=v
    const int hh = (nbase & 1023) >> 6;  // head
    float bj[4];
#pragma unroll
    for (int j = 0; j < 4; j++) bj[j] = bias[nbase + j * 16 + lr];
#pragma unroll
    for (int i = 0; i < 4; i++) {
      int growb = m0 + wm + i * 16 + 4 * lg;
#pragma unroll
      for (int r = 0; r < 4; r++) {
        int gr = growb + r;
        int bI = gr >> 11, t = gr & (Tdim - 1);
        size_t off = ((size_t)(bI * Hn + hh) * Tdim + t) * HSd;
        if (sec < 2) {
          u16* dst = (sec == 0) ? Qh : Kh;
#pragma unroll
          for (int j = 0; j < 2; j++) {  // RoPE pairs (d, d+32) = frags (j, j+2)
            int d = j * 16 + lr;
            float v1 = acc[i][j][r] + bj[j];
            float v2 = acc[i][j + 2][r] + bj[j + 2];
            float cs = cosT[t * 32 + d], sn = sinT[t * 32 + d];
            dst[off + d] = f2bf(v1 * cs - v2 * sn);
            dst[off + d + 32] = f2bf(v1 * sn + v2 * cs);
          }
        } else {
#pragma unroll
          for (int j = 0; j < 4; j++)
            Vh[off + j * 16 + lr] = f2bf(acc[i][j][r] + bj[j]);
        }
      }
    }
  } else {
#pragma unroll
    for (int i = 0; i < 4; i++) {
      int growb = m0 + wm + i * 16 + 4 * lg;
#pragma unroll
      for (int r = 0; r < 4; r++) {
        int gr = growb + r;
#pragma unroll
        for (int j = 0; j < 4; j++) {
          int col = nbase + j * 16 + lr;
          Out[(size_t)gr * Ndim + col] = acc[i][j][r] + bias[col];
        }
      }
    }
  }
}

// ---------------------------------------------------------------------------
// Flash attention: 1 wave per 16 q-rows, KVBLK=32, K/V direct from global
// (KV per head = 512KB, L2-resident). Online softmax; P via wave-private LDS.
__global__ __launch_bounds__(256, 2) void k_attn(const u16* __restrict__ Qh,
                                                 const u16* __restrict__ Kh,
                                                 const u16* __restrict__ Vt,
                                                 u16* __restrict__ ctx) {
  __shared__ u16 Plds[4][16][40];  // per-wave 16x32 P tile, padded (80B rows)
  const int tid = threadIdx.x;
  const int wid = tid >> 6, lane = tid & 63;
  const int lr = lane & 15, lg = lane >> 4;
  const int bh = blockIdx.y;
  const int qr0 = blockIdx.x * 64 + wid * 16;
  const u16* Q = Qh + (size_t)bh * Tdim * HSd;
  const u16* K = Kh + (size_t)bh * Tdim * HSd;
  const u16* V = Vt + (size_t)bh * HSd * Tdim;

  short8 qf0 = *(const short8*)(Q + (size_t)(qr0 + lr) * HSd + 8 * lg);
  short8 qf1 = *(const short8*)(Q + (size_t)(qr0 + lr) * HSd + 32 + 8 * lg);

  f32x4 ctxa[4] = {};
  float m2[4] = {-1e30f, -1e30f, -1e30f, -1e30f};
  float ssum[4] = {};
  const float SC = 0.125f * 1.44269504089f;  // scale * log2(e)
  const f32x4 zero = {};

  const int kv_end = qr0 + 16;  // causal: max kv = qr0+15 (all tile reads < T)
  for (int kv0 = 0; kv0 < kv_end; kv0 += 32) {
    f32x4 s[2];
#pragma unroll
    for (int f = 0; f < 2; f++) {
      const u16* Kr = K + (size_t)(kv0 + 16 * f + lr) * HSd;
      short8 kf0 = *(const short8*)(Kr + 8 * lg);
      short8 kf1 = *(const short8*)(Kr + 32 + 8 * lg);
      s[f] = __builtin_amdgcn_mfma_f32_16x16x32_bf16(qf0, kf0, zero, 0, 0, 0);
      s[f] = __builtin_amdgcn_mfma_f32_16x16x32_bf16(qf1, kf1, s[f], 0, 0, 0);
    }
    float pv[2][4];
#pragma unroll
    for (int r = 0; r < 4; r++) {
      int q = qr0 + 4 * lg + r;
      float s0 = (kv0 + lr <= q) ? s[0][r] * SC : -1e30f;
      float s1 = (kv0 + 16 + lr <= q) ? s[1][r] * SC : -1e30f;
      float tm = fmaxf(s0, s1);
      tm = fmaxf(tm, __shfl_xor(tm, 1));
      tm = fmaxf(tm, __shfl_xor(tm, 2));
      tm = fmaxf(tm, __shfl_xor(tm, 4));
      tm = fmaxf(tm, __shfl_xor(tm, 8));
      float mn = fmaxf(m2[r], tm);
      float alpha = __builtin_amdgcn_exp2f(m2[r] - mn);
      m2[r] = mn;
      float p0 = __builtin_amdgcn_exp2f(s0 - mn);
      float p1 = __builtin_amdgcn_exp2f(s1 - mn);
      float ps = p0 + p1;
      ps += __shfl_xor(ps, 1);
      ps += __shfl_xor(ps, 2);
      ps += __shfl_xor(ps, 4);
      ps += __shfl_xor(ps, 8);
      ssum[r] = ssum[r] * alpha + ps;
      pv[0][r] = p0;
      pv[1][r] = p1;
#pragma unroll
      for (int dt = 0; dt < 4; dt++) ctxa[dt][r] *= alpha;
    }
    // P (D-layout) -> LDS -> A-layout fragment
#pragma unroll
    for (int f = 0; f < 2; f++)
#pragma unroll
      for (int r = 0; r < 4; r++)
        Plds[wid][4 * lg + r][16 * f + lr] = f2bf(pv[f][r]);
    short8 pa = *(const short8*)(&Plds[wid][lr][8 * lg]);
#pragma unroll
    for (int dt = 0; dt < 4; dt++) {
      short8 vb =
          *(const short8*)(V + (size_t)(dt * 16 + lr) * Tdim + kv0 + 8 * lg);
      ctxa[dt] = __builtin_amdgcn_mfma_f32_16x16x32_bf16(pa, vb, ctxa[dt], 0, 0, 0);
    }
  }

  const int bI = bh >> 4, hh = bh & 15;
#pragma unroll
  for (int r = 0; r < 4; r++) {
    int t = qr0 + 4 * lg + r;
    float inv = 1.0f / ssum[r];
    size_t off = ((size_t)bI * Tdim + t) * Cdim + hh * HSd;
#pragma unroll
    for (int dt = 0; dt < 4; dt++)
      ctx[off + dt * 16 + lr] = f2bf(ctxa[dt][r] * inv);
  }
}

// ---------------------------------------------------------------------------
extern "C" void kernel_launch(void* const* d_in, const int* in_sizes, int n_in,
                              void* d_out, int out_size, void* d_ws,
                              size_t ws_size, hipStream_t stream) {
  const float* x = (const float*)d_in[0];
  const float* cosT = (const float*)d_in[1];
  const float* sinT = (const float*)d_in[2];
  const float* wattn = (const float*)d_in[3];
  const float* battn = (const float*)d_in[4];
  const float* wproj = (const float*)d_in[5];
  const float* bproj = (const float*)d_in[6];
  float* out = (float*)d_out;
  char* ws = (char*)d_ws;
  const size_t MB = 1024 * 1024;
  // workspace layout (48 MB total)
  u16* xb = (u16*)(ws + 0);        // 8 MB (dead after gemm1)
  u16* Vt = (u16*)(ws + 0);        // 8 MB (reuses xb region)
  u16* wattnT = (u16*)(ws + 8 * MB);   // 6 MB
  u16* wprojT = (u16*)(ws + 14 * MB);  // 2 MB
  u16* Qh = (u16*)(ws + 16 * MB);      // 8 MB
  u16* Kh = (u16*)(ws + 24 * MB);      // 8 MB
  u16* Vh = (u16*)(ws + 32 * MB);      // 8 MB
  u16* ctx = (u16*)(ws + 40 * MB);     // 8 MB

  k_convert_x<<<4096, 256, 0, stream>>>(x, xb);
  k_transpose_w<<<dim3(48, 16), 256, 0, stream>>>(wattn, wattnT, 1024, 3072);
  k_transpose_w<<<dim3(16, 16), 256, 0, stream>>>(wproj, wprojT, 1024, 1024);
  k_gemm<0><<<dim3(32, 24), 256, 0, stream>>>(xb, wattnT, battn, cosT, sinT, Qh,
                                              Kh, Vh, nullptr, 3072, 1024);
  k_transpose_v<<<dim3(32, 32), 256, 0, stream>>>(Vh, Vt);
  k_attn<<<dim3(32, 32), 256, 0, stream>>>(Qh, Kh, Vt, ctx);
  k_gemm<1><<<dim3(32, 8), 256, 0, stream>>>(ctx, wprojT, bproj, nullptr,
                                             nullptr, nullptr, nullptr, nullptr,
                                             out, 1024, 1024);
}

// Round 2
// 276.021 us; speedup vs baseline: 1.3902x; 1.3902x over previous
//
#include <hip/hip_runtime.h>
#include <hip/hip_bf16.h>

// Problem constants
#define Bn    2
#define Tdim  2048
#define Cdim  1024
#define Hn    16
#define HSd   64
#define Mrows 4096   // B*T

typedef unsigned short u16;
typedef __attribute__((ext_vector_type(8))) short short8;
typedef __attribute__((ext_vector_type(4))) float f32x4;

__device__ __forceinline__ u16 f2bf(float f) {
  union { __hip_bfloat16 h; u16 u; } cv;
  cv.h = __float2bfloat16(f);
  return cv.u;
}

#define GLOAD_LDS16(g, l)                                                     \
  __builtin_amdgcn_global_load_lds(                                           \
      (const __attribute__((address_space(1))) void*)(g),                     \
      (__attribute__((address_space(3))) void*)(l), 16, 0, 0)

// ---------------------------------------------------------------------------
// x (fp32, M x K row-major) -> bf16
__global__ __launch_bounds__(256) void k_convert_x(const float* __restrict__ x,
                                                   u16* __restrict__ xb) {
  int i = blockIdx.x * 256 + threadIdx.x;  // one float4 per thread
  float4 v = ((const float4*)x)[i];
  unsigned o0 = (unsigned)f2bf(v.x) | ((unsigned)f2bf(v.y) << 16);
  unsigned o1 = (unsigned)f2bf(v.z) | ((unsigned)f2bf(v.w) << 16);
  ((uint2*)xb)[i] = make_uint2(o0, o1);
}

// in: (R x Cc) fp32 row-major -> out: (Cc x R) bf16 row-major (N-major weights)
__global__ __launch_bounds__(256) void k_transpose_w(const float* __restrict__ in,
                                                     u16* __restrict__ out,
                                                     int R, int Cc) {
  __shared__ float tile[64][65];
  int c0 = blockIdx.x * 64, r0 = blockIdx.y * 64;
  int lc = threadIdx.x & 63, l0 = threadIdx.x >> 6;
  for (int rr = l0; rr < 64; rr += 4)
    tile[rr][lc] = in[(size_t)(r0 + rr) * Cc + c0 + lc];
  __syncthreads();
  for (int rr = l0; rr < 64; rr += 4)
    out[(size_t)(c0 + rr) * R + r0 + lc] = f2bf(tile[lc][rr]);
}

// Vh: [BH][T][64] bf16 -> Vt: [BH][64][T] bf16
__global__ __launch_bounds__(256) void k_transpose_v(const u16* __restrict__ Vh,
                                                     u16* __restrict__ Vt) {
  __shared__ u16 tile[64][72];
  int bh = blockIdx.y, t0 = blockIdx.x * 64;
  int lc = threadIdx.x & 63, l0 = threadIdx.x >> 6;
  const u16* src = Vh + (size_t)bh * Tdim * HSd;
  u16* dst = Vt + (size_t)bh * HSd * Tdim;
  for (int rr = l0; rr < 64; rr += 4)
    tile[rr][lc] = src[(size_t)(t0 + rr) * HSd + lc];
  __syncthreads();
  for (int dd = l0; dd < 64; dd += 4)
    dst[(size_t)dd * Tdim + t0 + lc] = tile[lc][dd];
}

// ---------------------------------------------------------------------------
// m97-structure GEMM: C[M,N] = A[M,K](bf16) * Bt[N,K](bf16)^T
// EPI 0: qkv epilogue (bias + RoPE, write Q/K head-major + V head-major, bf16)
// EPI 1: proj epilogue (bias, fp32 out)
template <int EPI>
__global__ __launch_bounds__(256, 2) void k_gemm(
    const u16* __restrict__ A, const u16* __restrict__ Bt,
    const float* __restrict__ bias, const float* __restrict__ cosT,
    const float* __restrict__ sinT, u16* __restrict__ Qh, u16* __restrict__ Kh,
    u16* __restrict__ Vh, float* __restrict__ Out, int Ndim, int Kdim) {
  __shared__ u16 As[128 * 32];
  __shared__ u16 Bs[128 * 32];
  const int tid = threadIdx.x;
  const int wid = tid >> 6, lane = tid & 63;
  const int m0 = blockIdx.x * 128, n0 = blockIdx.y * 128;
  const int wm = (wid >> 1) * 64, wn = (wid & 1) * 64;
  const int lr = lane & 15, lg = lane >> 4;

  f32x4 acc[4][4] = {};

  const u16* Ag = A + (size_t)m0 * Kdim;
  const u16* Bg = Bt + (size_t)n0 * Kdim;
  const int srow = lane >> 2, ske = (lane & 3) * 8;

  for (int k0 = 0; k0 < Kdim; k0 += 32) {
    for (int c = wid; c < 8; c += 4) {
      int row = c * 16 + srow;
      GLOAD_LDS16(Ag + (size_t)row * Kdim + k0 + ske, As + c * 512);
      GLOAD_LDS16(Bg + (size_t)row * Kdim + k0 + ske, Bs + c * 512);
    }
    __syncthreads();
    short8 a[4], b[4];
#pragma unroll
    for (int i = 0; i < 4; i++)
      a[i] = *(const short8*)(As + (wm + i * 16 + lr) * 32 + 8 * lg);
#pragma unroll
    for (int j = 0; j < 4; j++)
      b[j] = *(const short8*)(Bs + (wn + j * 16 + lr) * 32 + 8 * lg);
#pragma unroll
    for (int i = 0; i < 4; i++)
#pragma unroll
      for (int j = 0; j < 4; j++)
        acc[i][j] =
            __builtin_amdgcn_mfma_f32_16x16x32_bf16(a[i], b[j], acc[i][j], 0, 0, 0);
    __syncthreads();
  }

  const int nbase = n0 + wn;
  if (EPI == 0) {
    const int sec = nbase >> 10;         // 0=q 1=k 2=v
    const int hh = (nbase & 1023) >> 6;  // head
    float bj[4];
#pragma unroll
    for (int j = 0; j < 4; j++) bj[j] = bias[nbase + j * 16 + lr];
#pragma unroll
    for (int i = 0; i < 4; i++) {
      int growb = m0 + wm + i * 16 + 4 * lg;
#pragma unroll
      for (int r = 0; r < 4; r++) {
        int gr = growb + r;
        int bI = gr >> 11, t = gr & (Tdim - 1);
        size_t off = ((size_t)(bI * Hn + hh) * Tdim + t) * HSd;
        if (sec < 2) {
          u16* dst = (sec == 0) ? Qh : Kh;
#pragma unroll
          for (int j = 0; j < 2; j++) {
            int d = j * 16 + lr;
            float v1 = acc[i][j][r] + bj[j];
            float v2 = acc[i][j + 2][r] + bj[j + 2];
            float cs = cosT[t * 32 + d], sn = sinT[t * 32 + d];
            dst[off + d] = f2bf(v1 * cs - v2 * sn);
            dst[off + d + 32] = f2bf(v1 * sn + v2 * cs);
          }
        } else {
#pragma unroll
          for (int j = 0; j < 4; j++)
            Vh[off + j * 16 + lr] = f2bf(acc[i][j][r] + bj[j]);
        }
      }
    }
  } else {
#pragma unroll
    for (int i = 0; i < 4; i++) {
      int growb = m0 + wm + i * 16 + 4 * lg;
#pragma unroll
      for (int r = 0; r < 4; r++) {
        int gr = growb + r;
#pragma unroll
        for (int j = 0; j < 4; j++) {
          int col = nbase + j * 16 + lr;
          Out[(size_t)gr * Ndim + col] = acc[i][j][r] + bias[col];
        }
      }
    }
  }
}

// ---------------------------------------------------------------------------
// Flash attention v2: KVBLK=64, cooperative double-buffered LDS staging of
// K [64][64] and V^T [64][64] (shared by the 4 waves of a block), XOR-swizzled
// via pre-swizzled global source (global_load_lds writes linearly).
// Reversed blockIdx.x so heavy causal blocks launch first.
__global__ __launch_bounds__(256, 2) void k_attn(const u16* __restrict__ Qh,
                                                 const u16* __restrict__ Kh,
                                                 const u16* __restrict__ Vt,
                                                 u16* __restrict__ ctx) {
  __shared__ u16 Ks[2][64 * 64];
  __shared__ u16 Vs[2][64 * 64];
  __shared__ u16 Plds[4][16][72];  // per-wave 16x64 P tile, +8 pad (2-way=free)
  const int tid = threadIdx.x;
  const int wid = tid >> 6, lane = tid & 63;
  const int lr = lane & 15, lg = lane >> 4;
  const int bh = blockIdx.y;
  const int xt = gridDim.x - 1 - blockIdx.x;  // heavy blocks first
  const int qr0 = xt * 64 + wid * 16;
  const u16* Q = Qh + (size_t)bh * Tdim * HSd;
  const u16* K = Kh + (size_t)bh * Tdim * HSd;
  const u16* V = Vt + (size_t)bh * HSd * Tdim;

  short8 qf0 = *(const short8*)(Q + (size_t)(qr0 + lr) * HSd + 8 * lg);
  short8 qf1 = *(const short8*)(Q + (size_t)(qr0 + lr) * HSd + 32 + 8 * lg);

  // staging: per round c (2), wave stages 8 rows of K and 8 rows of V^T.
  // LDS linear [row][128B]; source col pre-swizzled so LDS[row][cb] holds
  // data[row][cb ^ ((row&7)<<4)].
  const int srow = wid * 8 + (lane >> 3);            // 0..31 (+32 for c=1)
  const int scol = 16 * ((lane & 7) ^ (lane >> 3));  // swizzled byte col

  f32x4 ctxa[4] = {};
  float m2[4] = {-1e30f, -1e30f, -1e30f, -1e30f};
  float ssum[4] = {};
  const float SC = 0.125f * 1.44269504089f;  // scale * log2(e)
  const f32x4 zero = {};
  const int swz = (lr & 7) << 4;

  const int nt = xt + 1;  // kv tiles of 64 for this block

#define STAGE_KV(b, kv0)                                                      \
  do {                                                                        \
    _Pragma("unroll") for (int c = 0; c < 2; ++c) {                           \
      int rr = c * 32 + srow;                                                 \
      GLOAD_LDS16((const char*)(K + (size_t)(kv0 + rr) * HSd) + scol,         \
                  Ks[b] + (c * 32 + wid * 8) * 64);                           \
      GLOAD_LDS16((const char*)(V + (size_t)rr * Tdim + (kv0)) + scol,        \
                  Vs[b] + (c * 32 + wid * 8) * 64);                           \
    }                                                                         \
  } while (0)

  STAGE_KV(0, 0);
  __syncthreads();

  int cur = 0;
  for (int it = 0; it < nt; ++it) {
    const int kv0 = it * 64;
    if (it + 1 < nt) STAGE_KV(cur ^ 1, kv0 + 64);

    const char* ksb = (const char*)(Ks[cur]);
    const char* vsb = (const char*)(Vs[cur]);

    // QK^T: S[16 q][64 kv]
    f32x4 s[4];
#pragma unroll
    for (int f = 0; f < 4; ++f) {
      int row = 16 * f + lr;
      int c0 = (lg * 16) ^ swz;
      short8 kf0 = *(const short8*)(ksb + row * 128 + c0);
      short8 kf1 = *(const short8*)(ksb + row * 128 + (c0 ^ 64));
      s[f] = __builtin_amdgcn_mfma_f32_16x16x32_bf16(qf0, kf0, zero, 0, 0, 0);
      s[f] = __builtin_amdgcn_mfma_f32_16x16x32_bf16(qf1, kf1, s[f], 0, 0, 0);
    }

    // online softmax (16-lane-group wave-parallel)
    float pv[4][4];
#pragma unroll
    for (int r = 0; r < 4; ++r) {
      int q = qr0 + 4 * lg + r;
      float sv[4];
#pragma unroll
      for (int f = 0; f < 4; ++f)
        sv[f] = (kv0 + 16 * f + lr <= q) ? s[f][r] * SC : -1e30f;
      float tm = fmaxf(fmaxf(sv[0], sv[1]), fmaxf(sv[2], sv[3]));
      tm = fmaxf(tm, __shfl_xor(tm, 1));
      tm = fmaxf(tm, __shfl_xor(tm, 2));
      tm = fmaxf(tm, __shfl_xor(tm, 4));
      tm = fmaxf(tm, __shfl_xor(tm, 8));
      float mn = fmaxf(m2[r], tm);
      float alpha = __builtin_amdgcn_exp2f(m2[r] - mn);
      m2[r] = mn;
      float ps = 0.f;
#pragma unroll
      for (int f = 0; f < 4; ++f) {
        pv[f][r] = __builtin_amdgcn_exp2f(sv[f] - mn);
        ps += pv[f][r];
      }
      ps += __shfl_xor(ps, 1);
      ps += __shfl_xor(ps, 2);
      ps += __shfl_xor(ps, 4);
      ps += __shfl_xor(ps, 8);
      ssum[r] = ssum[r] * alpha + ps;
#pragma unroll
      for (int dt = 0; dt < 4; dt++) ctxa[dt][r] *= alpha;
    }

    // P (D-layout) -> LDS -> A-layout fragments
#pragma unroll
    for (int f = 0; f < 4; ++f)
#pragma unroll
      for (int r = 0; r < 4; ++r)
        Plds[wid][4 * lg + r][16 * f + lr] = f2bf(pv[f][r]);
    const char* pb = (const char*)(&Plds[wid][0][0]);
    short8 pa0 = *(const short8*)(pb + lr * 144 + lg * 16);
    short8 pa1 = *(const short8*)(pb + lr * 144 + 64 + lg * 16);

    // PV: ctx[16 q][64 d] += P[16 q][64 kv] * V^T[64 d][64 kv]^T
#pragma unroll
    for (int dt = 0; dt < 4; ++dt) {
      int row = 16 * dt + lr;
      int c0 = (lg * 16) ^ swz;
      short8 vb0 = *(const short8*)(vsb + row * 128 + c0);
      short8 vb1 = *(const short8*)(vsb + row * 128 + (c0 ^ 64));
      ctxa[dt] = __builtin_amdgcn_mfma_f32_16x16x32_bf16(pa0, vb0, ctxa[dt], 0, 0, 0);
      ctxa[dt] = __builtin_amdgcn_mfma_f32_16x16x32_bf16(pa1, vb1, ctxa[dt], 0, 0, 0);
    }

    __syncthreads();  // drains vmcnt (staging) + lets all waves finish reads
    cur ^= 1;
  }
#undef STAGE_KV

  const int bI = bh >> 4, hh = bh & 15;
#pragma unroll
  for (int r = 0; r < 4; ++r) {
    int t = qr0 + 4 * lg + r;
    float inv = 1.0f / ssum[r];
    size_t off = ((size_t)bI * Tdim + t) * Cdim + hh * HSd;
#pragma unroll
    for (int dt = 0; dt < 4; dt++)
      ctx[off + dt * 16 + lr] = f2bf(ctxa[dt][r] * inv);
  }
}

// ---------------------------------------------------------------------------
extern "C" void kernel_launch(void* const* d_in, const int* in_sizes, int n_in,
                              void* d_out, int out_size, void* d_ws,
                              size_t ws_size, hipStream_t stream) {
  const float* x = (const float*)d_in[0];
  const float* cosT = (const float*)d_in[1];
  const float* sinT = (const float*)d_in[2];
  const float* wattn = (const float*)d_in[3];
  const float* battn = (const float*)d_in[4];
  const float* wproj = (const float*)d_in[5];
  const float* bproj = (const float*)d_in[6];
  float* out = (float*)d_out;
  char* ws = (char*)d_ws;
  const size_t MB = 1024 * 1024;
  u16* xb = (u16*)(ws + 0);            // 8 MB (dead after gemm1)
  u16* Vt = (u16*)(ws + 0);            // 8 MB (reuses xb region)
  u16* wattnT = (u16*)(ws + 8 * MB);   // 6 MB
  u16* wprojT = (u16*)(ws + 14 * MB);  // 2 MB
  u16* Qh = (u16*)(ws + 16 * MB);      // 8 MB
  u16* Kh = (u16*)(ws + 24 * MB);      // 8 MB
  u16* Vh = (u16*)(ws + 32 * MB);      // 8 MB
  u16* ctx = (u16*)(ws + 40 * MB);     // 8 MB

  k_convert_x<<<4096, 256, 0, stream>>>(x, xb);
  k_transpose_w<<<dim3(48, 16), 256, 0, stream>>>(wattn, wattnT, 1024, 3072);
  k_transpose_w<<<dim3(16, 16), 256, 0, stream>>>(wproj, wprojT, 1024, 1024);
  k_gemm<0><<<dim3(32, 24), 256, 0, stream>>>(xb, wattnT, battn, cosT, sinT, Qh,
                                              Kh, Vh, nullptr, 3072, 1024);
  k_transpose_v<<<dim3(32, 32), 256, 0, stream>>>(Vh, Vt);
  k_attn<<<dim3(32, 32), 256, 0, stream>>>(Qh, Kh, Vt, ctx);
  k_gemm<1><<<dim3(32, 8), 256, 0, stream>>>(ctx, wprojT, bproj, nullptr,
                                             nullptr, nullptr, nullptr, nullptr,
                                             out, 1024, 1024);
}

// Round 3
// 225.479 us; speedup vs baseline: 1.7019x; 1.2242x over previous
//
#include <hip/hip_runtime.h>
#include <hip/hip_bf16.h>

// Problem constants
#define Bn    2
#define Tdim  2048
#define Cdim  1024
#define Hn    16
#define HSd   64
#define Mrows 4096   // B*T

typedef unsigned short u16;
typedef __attribute__((ext_vector_type(8))) short short8;
typedef __attribute__((ext_vector_type(4))) float f32x4;

__device__ __forceinline__ u16 f2bf(float f) {
  union { __hip_bfloat16 h; u16 u; } cv;
  cv.h = __float2bfloat16(f);
  return cv.u;
}

#define GLOAD_LDS16(g, l)                                                     \
  __builtin_amdgcn_global_load_lds(                                           \
      (const __attribute__((address_space(1))) void*)(g),                     \
      (__attribute__((address_space(3))) void*)(l), 16, 0, 0)

// ---------------------------------------------------------------------------
// x (fp32, M x K row-major) -> bf16
__global__ __launch_bounds__(256) void k_convert_x(const float* __restrict__ x,
                                                   u16* __restrict__ xb) {
  int i = blockIdx.x * 256 + threadIdx.x;  // one float4 per thread
  float4 v = ((const float4*)x)[i];
  unsigned o0 = (unsigned)f2bf(v.x) | ((unsigned)f2bf(v.y) << 16);
  unsigned o1 = (unsigned)f2bf(v.z) | ((unsigned)f2bf(v.w) << 16);
  ((uint2*)xb)[i] = make_uint2(o0, o1);
}

// in: (R x Cc) fp32 row-major -> out: (Cc x R) bf16 row-major (N-major weights)
__global__ __launch_bounds__(256) void k_transpose_w(const float* __restrict__ in,
                                                     u16* __restrict__ out,
                                                     int R, int Cc) {
  __shared__ float tile[64][65];
  int c0 = blockIdx.x * 64, r0 = blockIdx.y * 64;
  int lc = threadIdx.x & 63, l0 = threadIdx.x >> 6;
  for (int rr = l0; rr < 64; rr += 4)
    tile[rr][lc] = in[(size_t)(r0 + rr) * Cc + c0 + lc];
  __syncthreads();
  for (int rr = l0; rr < 64; rr += 4)
    out[(size_t)(c0 + rr) * R + r0 + lc] = f2bf(tile[lc][rr]);
}

// Vh: [BH][T][64] bf16 -> Vt: [BH][64][T] bf16
__global__ __launch_bounds__(256) void k_transpose_v(const u16* __restrict__ Vh,
                                                     u16* __restrict__ Vt) {
  __shared__ u16 tile[64][72];
  int bh = blockIdx.y, t0 = blockIdx.x * 64;
  int lc = threadIdx.x & 63, l0 = threadIdx.x >> 6;
  const u16* src = Vh + (size_t)bh * Tdim * HSd;
  u16* dst = Vt + (size_t)bh * HSd * Tdim;
  for (int rr = l0; rr < 64; rr += 4)
    tile[rr][lc] = src[(size_t)(t0 + rr) * HSd + lc];
  __syncthreads();
  for (int dd = l0; dd < 64; dd += 4)
    dst[(size_t)dd * Tdim + t0 + lc] = tile[lc][dd];
}

// ---------------------------------------------------------------------------
// m97-structure GEMM: C[M,N] = A[M,K](bf16) * Bt[N,K](bf16)^T
// EPI 0: qkv epilogue (bias + RoPE + Q-prescale 1/8, head-major bf16 out)
// EPI 1: proj epilogue (bias, fp32 out)
template <int EPI>
__global__ __launch_bounds__(256, 2) void k_gemm(
    const u16* __restrict__ A, const u16* __restrict__ Bt,
    const float* __restrict__ bias, const float* __restrict__ cosT,
    const float* __restrict__ sinT, u16* __restrict__ Qh, u16* __restrict__ Kh,
    u16* __restrict__ Vh, float* __restrict__ Out, int Ndim, int Kdim) {
  __shared__ u16 As[128 * 32];
  __shared__ u16 Bs[128 * 32];
  const int tid = threadIdx.x;
  const int wid = tid >> 6, lane = tid & 63;
  const int m0 = blockIdx.x * 128, n0 = blockIdx.y * 128;
  const int wm = (wid >> 1) * 64, wn = (wid & 1) * 64;
  const int lr = lane & 15, lg = lane >> 4;

  f32x4 acc[4][4] = {};

  const u16* Ag = A + (size_t)m0 * Kdim;
  const u16* Bg = Bt + (size_t)n0 * Kdim;
  const int srow = lane >> 2, ske = (lane & 3) * 8;

  for (int k0 = 0; k0 < Kdim; k0 += 32) {
    for (int c = wid; c < 8; c += 4) {
      int row = c * 16 + srow;
      GLOAD_LDS16(Ag + (size_t)row * Kdim + k0 + ske, As + c * 512);
      GLOAD_LDS16(Bg + (size_t)row * Kdim + k0 + ske, Bs + c * 512);
    }
    __syncthreads();
    short8 a[4], b[4];
#pragma unroll
    for (int i = 0; i < 4; i++)
      a[i] = *(const short8*)(As + (wm + i * 16 + lr) * 32 + 8 * lg);
#pragma unroll
    for (int j = 0; j < 4; j++)
      b[j] = *(const short8*)(Bs + (wn + j * 16 + lr) * 32 + 8 * lg);
#pragma unroll
    for (int i = 0; i < 4; i++)
#pragma unroll
      for (int j = 0; j < 4; j++)
        acc[i][j] =
            __builtin_amdgcn_mfma_f32_16x16x32_bf16(a[i], b[j], acc[i][j], 0, 0, 0);
    __syncthreads();
  }

  const int nbase = n0 + wn;
  if (EPI == 0) {
    const int sec = nbase >> 10;         // 0=q 1=k 2=v
    const int hh = (nbase & 1023) >> 6;  // head
    const float qs = (sec == 0) ? 0.125f : 1.0f;  // fold 1/sqrt(HS) into Q
    float bj[4];
#pragma unroll
    for (int j = 0; j < 4; j++) bj[j] = bias[nbase + j * 16 + lr];
#pragma unroll
    for (int i = 0; i < 4; i++) {
      int growb = m0 + wm + i * 16 + 4 * lg;
#pragma unroll
      for (int r = 0; r < 4; r++) {
        int gr = growb + r;
        int bI = gr >> 11, t = gr & (Tdim - 1);
        size_t off = ((size_t)(bI * Hn + hh) * Tdim + t) * HSd;
        if (sec < 2) {
          u16* dst = (sec == 0) ? Qh : Kh;
#pragma unroll
          for (int j = 0; j < 2; j++) {
            int d = j * 16 + lr;
            float v1 = acc[i][j][r] + bj[j];
            float v2 = acc[i][j + 2][r] + bj[j + 2];
            float cs = cosT[t * 32 + d], sn = sinT[t * 32 + d];
            dst[off + d] = f2bf((v1 * cs - v2 * sn) * qs);
            dst[off + d + 32] = f2bf((v1 * sn + v2 * cs) * qs);
          }
        } else {
#pragma unroll
          for (int j = 0; j < 4; j++)
            Vh[off + j * 16 + lr] = f2bf(acc[i][j][r] + bj[j]);
        }
      }
    }
  } else {
#pragma unroll
    for (int i = 0; i < 4; i++) {
      int growb = m0 + wm + i * 16 + 4 * lg;
#pragma unroll
      for (int r = 0; r < 4; r++) {
        int gr = growb + r;
#pragma unroll
        for (int j = 0; j < 4; j++) {
          int col = nbase + j * 16 + lr;
          Out[(size_t)gr * Ndim + col] = acc[i][j][r] + bias[col];
        }
      }
    }
  }
}

// ---------------------------------------------------------------------------
// Flash attention v3: 8 waves/block, QBLK=128, KVBLK=64, double-buffered
// XOR-swizzled K/V^T staging shared by 8 waves, globally heavy-first 1D grid.
// Softmax: maskless fast path off-diagonal, per-lane deferred denominator,
// exact defer-rescale (skip alpha pass when max didn't grow).
__global__ __launch_bounds__(512, 4) void k_attn(const u16* __restrict__ Qh,
                                                 const u16* __restrict__ Kh,
                                                 const u16* __restrict__ Vt,
                                                 u16* __restrict__ ctx) {
  __shared__ u16 Ks[2][64 * 64];
  __shared__ u16 Vs[2][64 * 64];
  __shared__ u16 Plds[8][16][72];  // per-wave 16x64 P tile, +8 pad
  const int tid = threadIdx.x;
  const int wid = tid >> 6, lane = tid & 63;
  const int lr = lane & 15, lg = lane >> 4;
  const int bid = blockIdx.x;
  const int xb = 15 - (bid >> 5);  // heavy q-blocks dispatched first
  const int bh = bid & 31;
  const int qr0 = xb * 128 + wid * 16;
  const int nt = 2 * xb + 2;       // kv tiles of 64
  const int itd = qr0 >> 6;        // this wave's diagonal tile
  const u16* Q = Qh + (size_t)bh * Tdim * HSd;
  const u16* K = Kh + (size_t)bh * Tdim * HSd;
  const u16* V = Vt + (size_t)bh * HSd * Tdim;

  short8 qf0 = *(const short8*)(Q + (size_t)(qr0 + lr) * HSd + 8 * lg);
  short8 qf1 = *(const short8*)(Q + (size_t)(qr0 + lr) * HSd + 32 + 8 * lg);

  // Each wave stages 8 rows of K-tile and 8 rows of V^T-tile per buffer.
  // LDS invariant: LDS[row][cb] = data[row][cb ^ ((row&7)<<4)] (byte cols).
  const int srow = lane >> 3;                        // 0..7 within wave's 8 rows
  const int scol = 16 * ((lane & 7) ^ srow);         // pre-swizzled byte col
  const int swz = (lr & 7) << 4;

  f32x4 ctxa[4] = {};
  float m2[4] = {-1e30f, -1e30f, -1e30f, -1e30f};
  float m2L[4] = {-1e30f, -1e30f, -1e30f, -1e30f};
  float ssum[4] = {0.f, 0.f, 0.f, 0.f};  // per-lane partials
  const float L2E = 1.44269504089f;
  const f32x4 zero = {};

#define STAGE_KV(b, kv0)                                                      \
  do {                                                                        \
    GLOAD_LDS16((const char*)(K + (size_t)((kv0) + wid * 8 + srow) * HSd) +   \
                    scol,                                                     \
                Ks[b] + wid * 8 * 64);                                        \
    GLOAD_LDS16((const char*)(V + (size_t)(wid * 8 + srow) * Tdim + (kv0)) +  \
                    scol,                                                     \
                Vs[b] + wid * 8 * 64);                                        \
  } while (0)

  STAGE_KV(0, 0);
  __syncthreads();

  int cur = 0;
  for (int it = 0; it < nt; ++it) {
    const int kv0 = it * 64;
    if (it + 1 < nt) STAGE_KV(cur ^ 1, kv0 + 64);

    if (it <= itd) {
      const char* ksb = (const char*)(Ks[cur]);
      const char* vsb = (const char*)(Vs[cur]);

      // QK^T: S[16 q][64 kv]
      f32x4 s[4];
#pragma unroll
      for (int f = 0; f < 4; ++f) {
        int row = 16 * f + lr;
        int c0 = (lg * 16) ^ swz;
        short8 kf0 = *(const short8*)(ksb + row * 128 + c0);
        short8 kf1 = *(const short8*)(ksb + row * 128 + (c0 ^ 64));
        s[f] = __builtin_amdgcn_mfma_f32_16x16x32_bf16(qf0, kf0, zero, 0, 0, 0);
        s[f] = __builtin_amdgcn_mfma_f32_16x16x32_bf16(qf1, kf1, s[f], 0, 0, 0);
      }

      // row maxes (16-lane groups)
      float sv[4][4], tm[4];
#pragma unroll
      for (int r = 0; r < 4; ++r) {
        if (it == itd) {
          int q = qr0 + 4 * lg + r;
#pragma unroll
          for (int f = 0; f < 4; ++f)
            sv[f][r] = (kv0 + 16 * f + lr <= q) ? s[f][r] : -1e30f;
        } else {
#pragma unroll
          for (int f = 0; f < 4; ++f) sv[f][r] = s[f][r];
        }
        float t = fmaxf(fmaxf(sv[0][r], sv[1][r]), fmaxf(sv[2][r], sv[3][r]));
        t = fmaxf(t, __shfl_xor(t, 1));
        t = fmaxf(t, __shfl_xor(t, 2));
        t = fmaxf(t, __shfl_xor(t, 4));
        t = fmaxf(t, __shfl_xor(t, 8));
        tm[r] = t;
      }

      // exact defer-rescale: only touch ctx/ssum when a max actually grew
      bool up = (tm[0] > m2[0]) | (tm[1] > m2[1]) | (tm[2] > m2[2]) |
                (tm[3] > m2[3]);
      if (__any(up)) {
#pragma unroll
        for (int r = 0; r < 4; ++r) {
          float mn = fmaxf(m2[r], tm[r]);
          float alpha = __builtin_amdgcn_exp2f((m2[r] - mn) * L2E);
          m2[r] = mn;
          m2L[r] = mn * L2E;
          ssum[r] *= alpha;
#pragma unroll
          for (int dt = 0; dt < 4; ++dt) ctxa[dt][r] *= alpha;
        }
      }

      // P = exp(S - m), per-lane partial denominator, store P to LDS
#pragma unroll
      for (int r = 0; r < 4; ++r) {
#pragma unroll
        for (int f = 0; f < 4; ++f) {
          float p = __builtin_amdgcn_exp2f(fmaf(sv[f][r], L2E, -m2L[r]));
          ssum[r] += p;
          Plds[wid][4 * lg + r][16 * f + lr] = f2bf(p);
        }
      }

      const char* pb = (const char*)(&Plds[wid][0][0]);
      short8 pa0 = *(const short8*)(pb + lr * 144 + lg * 16);
      short8 pa1 = *(const short8*)(pb + lr * 144 + 64 + lg * 16);

      // PV: ctx[16 q][64 d] += P[16 q][64 kv] * V^T[64 d][64 kv]^T
#pragma unroll
      for (int dt = 0; dt < 4; ++dt) {
        int row = 16 * dt + lr;
        int c0 = (lg * 16) ^ swz;
        short8 vb0 = *(const short8*)(vsb + row * 128 + c0);
        short8 vb1 = *(const short8*)(vsb + row * 128 + (c0 ^ 64));
        ctxa[dt] =
            __builtin_amdgcn_mfma_f32_16x16x32_bf16(pa0, vb0, ctxa[dt], 0, 0, 0);
        ctxa[dt] =
            __builtin_amdgcn_mfma_f32_16x16x32_bf16(pa1, vb1, ctxa[dt], 0, 0, 0);
      }
    }

    __syncthreads();
    cur ^= 1;
  }
#undef STAGE_KV

  const int bI = bh >> 4, hh = bh & 15;
#pragma unroll
  for (int r = 0; r < 4; ++r) {
    float s = ssum[r];
    s += __shfl_xor(s, 1);
    s += __shfl_xor(s, 2);
    s += __shfl_xor(s, 4);
    s += __shfl_xor(s, 8);
    float inv = 1.0f / s;
    int t = qr0 + 4 * lg + r;
    size_t off = ((size_t)bI * Tdim + t) * Cdim + hh * HSd;
#pragma unroll
    for (int dt = 0; dt < 4; dt++)
      ctx[off + dt * 16 + lr] = f2bf(ctxa[dt][r] * inv);
  }
}

// ---------------------------------------------------------------------------
extern "C" void kernel_launch(void* const* d_in, const int* in_sizes, int n_in,
                              void* d_out, int out_size, void* d_ws,
                              size_t ws_size, hipStream_t stream) {
  const float* x = (const float*)d_in[0];
  const float* cosT = (const float*)d_in[1];
  const float* sinT = (const float*)d_in[2];
  const float* wattn = (const float*)d_in[3];
  const float* battn = (const float*)d_in[4];
  const float* wproj = (const float*)d_in[5];
  const float* bproj = (const float*)d_in[6];
  float* out = (float*)d_out;
  char* ws = (char*)d_ws;
  const size_t MB = 1024 * 1024;
  u16* xb = (u16*)(ws + 0);            // 8 MB (dead after gemm1)
  u16* Vt = (u16*)(ws + 0);            // 8 MB (reuses xb region)
  u16* wattnT = (u16*)(ws + 8 * MB);   // 6 MB
  u16* wprojT = (u16*)(ws + 14 * MB);  // 2 MB
  u16* Qh = (u16*)(ws + 16 * MB);      // 8 MB
  u16* Kh = (u16*)(ws + 24 * MB);      // 8 MB
  u16* Vh = (u16*)(ws + 32 * MB);      // 8 MB
  u16* ctx = (u16*)(ws + 40 * MB);     // 8 MB

  k_convert_x<<<4096, 256, 0, stream>>>(x, xb);
  k_transpose_w<<<dim3(48, 16), 256, 0, stream>>>(wattn, wattnT, 1024, 3072);
  k_transpose_w<<<dim3(16, 16), 256, 0, stream>>>(wproj, wprojT, 1024, 1024);
  k_gemm<0><<<dim3(32, 24), 256, 0, stream>>>(xb, wattnT, battn, cosT, sinT, Qh,
                                              Kh, Vh, nullptr, 3072, 1024);
  k_transpose_v<<<dim3(32, 32), 256, 0, stream>>>(Vh, Vt);
  k_attn<<<512, 512, 0, stream>>>(Qh, Kh, Vt, ctx);
  k_gemm<1><<<dim3(32, 8), 256, 0, stream>>>(ctx, wprojT, bproj, nullptr,
                                             nullptr, nullptr, nullptr, nullptr,
                                             out, 1024, 1024);
}